// Round 1
// baseline (366.385 us; speedup 1.0000x reference)
//
#include <hip/hip_runtime.h>

// Problem: B=32, T=2048, D=1024 (fp32 in/out)
// out = [context (B*D), attention_weights (B*T)]  (fp32, concatenated)
#define BB 32
#define TT 2048
#define DD 1024
#define TCHUNK 32               // rows per wave
#define NC (TT / TCHUNK)        // 64 chunks per batch
#define WPB 4                   // waves per block (256 threads)
#define BLOCKS_PER_B (NC / WPB) // 16
#define GR 8                    // rows per group (burst unit: 32 KiB contiguous)
#define NG (TCHUNK / GR)        // 4 groups per chunk

// Workspace layout (fp32):
//   scores : B*T           (65536)
//   pm     : B*NC          (2048)
//   pl     : B*NC          (2048)
//   pctx   : B*NC*D        (2097152)
// total ~8.4 MiB

__global__ __launch_bounds__(256, 2) void attn_pass1(
    const float* __restrict__ query,
    const float* __restrict__ values,
    float* __restrict__ ws) {
    float* scores = ws;
    float* pm = ws + BB * TT;
    float* pl = pm + BB * NC;
    float* pctx = pl + BB * NC;

    const int tid  = threadIdx.x;
    const int lane = tid & 63;
    const int wave = tid >> 6;
    const int b     = blockIdx.x / BLOCKS_PER_B;
    const int chunk = (blockIdx.x % BLOCKS_PER_B) * WPB + wave;
    const int t0    = chunk * TCHUNK;

    // Query fragment: lane covers d in {q*256 + 4*lane + j : q=0..3, j=0..3}
    const float4* qrow = (const float4*)(query + (size_t)b * DD);
    float qf[16];
#pragma unroll
    for (int q = 0; q < 4; q++) {
        float4 q4 = qrow[q * 64 + lane];
        qf[4 * q + 0] = q4.x; qf[4 * q + 1] = q4.y;
        qf[4 * q + 2] = q4.z; qf[4 * q + 3] = q4.w;
    }

    const float4* vbase = (const float4*)(values + ((size_t)b * TT + t0) * DD);
    // row stride = D/4 = 256 float4

    float m = -INFINITY, l = 0.f;
    float ctx[16];
#pragma unroll
    for (int k = 0; k < 16; k++) ctx[k] = 0.f;

    for (int gi = 0; gi < NG; ++gi) {
        const int r0 = gi * GR;

        // ---- burst-load 8 rows (32 KiB contiguous per wave) ----
        float4 v4[GR][4];
#pragma unroll
        for (int r = 0; r < GR; ++r)
#pragma unroll
            for (int q = 0; q < 4; ++q)
                v4[r][q] = vbase[(size_t)(r0 + r) * 256 + q * 64 + lane];

        // ---- 8 per-lane partial dots (independent FMA chains) ----
        float s[GR];
#pragma unroll
        for (int r = 0; r < GR; ++r) {
            float acc = 0.f;
#pragma unroll
            for (int q = 0; q < 4; ++q) {
                acc = fmaf(qf[4 * q + 0], v4[r][q].x, acc);
                acc = fmaf(qf[4 * q + 1], v4[r][q].y, acc);
                acc = fmaf(qf[4 * q + 2], v4[r][q].z, acc);
                acc = fmaf(qf[4 * q + 3], v4[r][q].w, acc);
            }
            s[r] = acc;
        }

        // ---- 8 pipelined butterfly reductions ----
#pragma unroll
        for (int off = 32; off >= 1; off >>= 1)
#pragma unroll
            for (int r = 0; r < GR; ++r)
                s[r] += __shfl_xor(s[r], off, 64);

        // ---- branch-free group-amortized online softmax ----
        float m01 = fmaxf(s[0], s[1]), m23 = fmaxf(s[2], s[3]);
        float m45 = fmaxf(s[4], s[5]), m67 = fmaxf(s[6], s[7]);
        float gm = fmaxf(fmaxf(m01, m23), fmaxf(m45, m67));

        float mnew = fmaxf(m, gm);
        float corr = __expf(m - mnew);   // first group: exp(-inf)=0
        m = mnew;
        l *= corr;

        float p[GR];
#pragma unroll
        for (int r = 0; r < GR; ++r) { p[r] = __expf(s[r] - m); l += p[r]; }

#pragma unroll
        for (int k = 0; k < 16; k++) ctx[k] *= corr;
#pragma unroll
        for (int r = 0; r < GR; ++r) {
#pragma unroll
            for (int q = 0; q < 4; ++q) {
                ctx[4 * q + 0] = fmaf(p[r], v4[r][q].x, ctx[4 * q + 0]);
                ctx[4 * q + 1] = fmaf(p[r], v4[r][q].y, ctx[4 * q + 1]);
                ctx[4 * q + 2] = fmaf(p[r], v4[r][q].z, ctx[4 * q + 2]);
                ctx[4 * q + 3] = fmaf(p[r], v4[r][q].w, ctx[4 * q + 3]);
            }
        }

        // raw scores for pass2 weights (s[] is wave-uniform after butterfly)
        if (lane == 0) {
            float4* sp = (float4*)(scores + (size_t)b * TT + t0 + r0);
            sp[0] = make_float4(s[0], s[1], s[2], s[3]);
            sp[1] = make_float4(s[4], s[5], s[6], s[7]);
        }
    }

    const int ci = b * NC + chunk;
    if (lane == 0) { pm[ci] = m; pl[ci] = l; }
    float4* pc = (float4*)(pctx + (size_t)ci * DD);
#pragma unroll
    for (int q = 0; q < 4; q++)
        pc[q * 64 + lane] = make_float4(ctx[4 * q + 0], ctx[4 * q + 1],
                                        ctx[4 * q + 2], ctx[4 * q + 3]);
}

__global__ __launch_bounds__(256) void attn_pass2(
    const float* __restrict__ ws,
    float* __restrict__ out) {
    const float* scores = ws;
    const float* pm = ws + BB * TT;
    const float* pl = pm + BB * NC;
    const float* pctx = pl + BB * NC;

    const int tid   = threadIdx.x;
    const int b     = blockIdx.x >> 2;
    const int slice = blockIdx.x & 3;

    __shared__ float s_e[NC];
    __shared__ float s_M, s_L;
    if (tid < 64) {  // wave 0: reduce the 64 chunk partials
        float mi = pm[b * NC + tid];
        float li = pl[b * NC + tid];
        float M = mi;
#pragma unroll
        for (int off = 32; off >= 1; off >>= 1) M = fmaxf(M, __shfl_xor(M, off, 64));
        float e  = __expf(mi - M);
        float lw = li * e;
#pragma unroll
        for (int off = 32; off >= 1; off >>= 1) lw += __shfl_xor(lw, off, 64);
        s_e[tid] = e;
        if (tid == 0) { s_M = M; s_L = lw; }
    }
    __syncthreads();
    const float M  = s_M;
    const float rL = 1.0f / s_L;

    // context slice: d = slice*256 + tid
    const int d = slice * 256 + tid;
    const float* base = pctx + (size_t)b * NC * DD + d;
    float acc = 0.f;
#pragma unroll 8
    for (int i = 0; i < NC; i++) acc = fmaf(base[(size_t)i * DD], s_e[i], acc);
    out[(size_t)b * DD + d] = acc * rL;

    // weights: t = slice*512 + k*256 + tid
    float* wout = out + BB * DD;
#pragma unroll
    for (int k = 0; k < 2; k++) {
        int t = slice * 512 + k * 256 + tid;
        float w = __expf(scores[(size_t)b * TT + t] - M) * rL;
        wout[(size_t)b * TT + t] = w;
    }
}

extern "C" void kernel_launch(void* const* d_in, const int* in_sizes, int n_in,
                              void* d_out, int out_size, void* d_ws, size_t ws_size,
                              hipStream_t stream) {
    const float* query  = (const float*)d_in[0];
    const float* values = (const float*)d_in[1];
    float* ws = (float*)d_ws;
    float* out = (float*)d_out;

    attn_pass1<<<dim3(BB * BLOCKS_PER_B), dim3(256), 0, stream>>>(query, values, ws);
    attn_pass2<<<dim3(BB * 4), dim3(256), 0, stream>>>(ws, out);
}

// Round 2
// 363.476 us; speedup vs baseline: 1.0080x; 1.0080x over previous
//
#include <hip/hip_runtime.h>

// Problem: B=32, T=2048, D=1024 (fp32 in/out)
// out = [context (B*D), attention_weights (B*T)]  (fp32, concatenated)
#define BB 32
#define TT 2048
#define DD 1024
#define TCHUNK 32               // rows per wave
#define NC (TT / TCHUNK)        // 64 chunks per batch
#define WPB 4                   // waves per block (256 threads)
#define BLOCKS_PER_B (NC / WPB) // 16 blocks per batch
#define NP BLOCKS_PER_B         // 16 partials per batch (block-combined)
#define GR 8                    // rows per group (burst unit: 32 KiB contiguous)
#define NG (TCHUNK / GR)        // 4 groups per chunk

// Workspace layout (fp32):
//   scores : B*T            (65536)
//   pm     : B*NP           (512)
//   pl     : B*NP           (512)
//   pctx   : B*NP*D         (524288)
// total ~2.3 MiB

__global__ __launch_bounds__(256, 2) void attn_pass1(
    const float* __restrict__ query,
    const float* __restrict__ values,
    float* __restrict__ ws) {
    float* scores = ws;
    float* pm = ws + BB * TT;
    float* pl = pm + BB * NP;
    float* pctx = pl + BB * NP;

    const int tid  = threadIdx.x;
    const int lane = tid & 63;
    const int wave = tid >> 6;
    const int b      = blockIdx.x / BLOCKS_PER_B;
    const int blkInB = blockIdx.x % BLOCKS_PER_B;
    const int chunk  = blkInB * WPB + wave;
    const int t0     = chunk * TCHUNK;

    // Query fragment: lane covers d in {q*256 + 4*lane + j : q=0..3, j=0..3}
    const float4* qrow = (const float4*)(query + (size_t)b * DD);
    float qf[16];
#pragma unroll
    for (int q = 0; q < 4; q++) {
        float4 q4 = qrow[q * 64 + lane];
        qf[4 * q + 0] = q4.x; qf[4 * q + 1] = q4.y;
        qf[4 * q + 2] = q4.z; qf[4 * q + 3] = q4.w;
    }

    const float4* vbase = (const float4*)(values + ((size_t)b * TT + t0) * DD);
    // row stride = D/4 = 256 float4

    float m = -INFINITY, l = 0.f;
    float ctx[16];
#pragma unroll
    for (int k = 0; k < 16; k++) ctx[k] = 0.f;

    for (int gi = 0; gi < NG; ++gi) {
        const int r0 = gi * GR;

        // ---- burst-load 8 rows (32 KiB contiguous per wave) ----
        float4 v4[GR][4];
#pragma unroll
        for (int r = 0; r < GR; ++r)
#pragma unroll
            for (int q = 0; q < 4; ++q)
                v4[r][q] = vbase[(size_t)(r0 + r) * 256 + q * 64 + lane];

        // ---- 8 per-lane partial dots (independent FMA chains) ----
        float s[GR];
#pragma unroll
        for (int r = 0; r < GR; ++r) {
            float acc = 0.f;
#pragma unroll
            for (int q = 0; q < 4; ++q) {
                acc = fmaf(qf[4 * q + 0], v4[r][q].x, acc);
                acc = fmaf(qf[4 * q + 1], v4[r][q].y, acc);
                acc = fmaf(qf[4 * q + 2], v4[r][q].z, acc);
                acc = fmaf(qf[4 * q + 3], v4[r][q].w, acc);
            }
            s[r] = acc;
        }

        // ---- 8 pipelined butterfly reductions ----
#pragma unroll
        for (int off = 32; off >= 1; off >>= 1)
#pragma unroll
            for (int r = 0; r < GR; ++r)
                s[r] += __shfl_xor(s[r], off, 64);

        // ---- branch-free group-amortized online softmax ----
        float m01 = fmaxf(s[0], s[1]), m23 = fmaxf(s[2], s[3]);
        float m45 = fmaxf(s[4], s[5]), m67 = fmaxf(s[6], s[7]);
        float gm = fmaxf(fmaxf(m01, m23), fmaxf(m45, m67));

        float mnew = fmaxf(m, gm);
        float corr = __expf(m - mnew);   // first group: exp(-inf)=0
        m = mnew;
        l *= corr;

        float p[GR];
#pragma unroll
        for (int r = 0; r < GR; ++r) { p[r] = __expf(s[r] - m); l += p[r]; }

#pragma unroll
        for (int k = 0; k < 16; k++) ctx[k] *= corr;
#pragma unroll
        for (int r = 0; r < GR; ++r) {
#pragma unroll
            for (int q = 0; q < 4; ++q) {
                ctx[4 * q + 0] = fmaf(p[r], v4[r][q].x, ctx[4 * q + 0]);
                ctx[4 * q + 1] = fmaf(p[r], v4[r][q].y, ctx[4 * q + 1]);
                ctx[4 * q + 2] = fmaf(p[r], v4[r][q].z, ctx[4 * q + 2]);
                ctx[4 * q + 3] = fmaf(p[r], v4[r][q].w, ctx[4 * q + 3]);
            }
        }

        // raw scores for pass2 weights (s[] is wave-uniform after butterfly)
        if (lane == 0) {
            float4* sp = (float4*)(scores + (size_t)b * TT + t0 + r0);
            sp[0] = make_float4(s[0], s[1], s[2], s[3]);
            sp[1] = make_float4(s[4], s[5], s[6], s[7]);
        }
    }

    // ---- block-level combine: 4 wave states -> 1 partial per block ----
    __shared__ float cbuf[WPB][DD];   // 16 KB
    __shared__ float cm[WPB], cl[WPB];
    float* crow = cbuf[wave];
#pragma unroll
    for (int q = 0; q < 4; q++)
        ((float4*)(crow + q * 256))[lane] =
            make_float4(ctx[4 * q + 0], ctx[4 * q + 1],
                        ctx[4 * q + 2], ctx[4 * q + 3]);
    if (lane == 0) { cm[wave] = m; cl[wave] = l; }
    __syncthreads();

    const float m0 = cm[0], m1 = cm[1], m2 = cm[2], m3 = cm[3];
    const float M = fmaxf(fmaxf(m0, m1), fmaxf(m2, m3));
    const float e0 = __expf(m0 - M), e1 = __expf(m1 - M);
    const float e2 = __expf(m2 - M), e3 = __expf(m3 - M);

    const int ci = b * NP + blkInB;
    if (tid == 0) {
        pm[ci] = M;
        pl[ci] = fmaf(cl[0], e0, fmaf(cl[1], e1, fmaf(cl[2], e2, cl[3] * e3)));
    }

    // thread tid combines d = 4*tid .. 4*tid+3
    float4 c0 = ((float4*)cbuf[0])[tid];
    float4 c1 = ((float4*)cbuf[1])[tid];
    float4 c2 = ((float4*)cbuf[2])[tid];
    float4 c3 = ((float4*)cbuf[3])[tid];
    float4 o;
    o.x = fmaf(c0.x, e0, fmaf(c1.x, e1, fmaf(c2.x, e2, c3.x * e3)));
    o.y = fmaf(c0.y, e0, fmaf(c1.y, e1, fmaf(c2.y, e2, c3.y * e3)));
    o.z = fmaf(c0.z, e0, fmaf(c1.z, e1, fmaf(c2.z, e2, c3.z * e3)));
    o.w = fmaf(c0.w, e0, fmaf(c1.w, e1, fmaf(c2.w, e2, c3.w * e3)));
    ((float4*)(pctx + (size_t)ci * DD))[tid] = o;
}

__global__ __launch_bounds__(256) void attn_pass2(
    const float* __restrict__ ws,
    float* __restrict__ out) {
    const float* scores = ws;
    const float* pm = ws + BB * TT;
    const float* pl = pm + BB * NP;
    const float* pctx = pl + BB * NP;

    const int tid   = threadIdx.x;
    const int b     = blockIdx.x >> 2;
    const int slice = blockIdx.x & 3;

    __shared__ float s_e[NP];
    __shared__ float s_M, s_L;
    if (tid < 64) {  // wave 0: reduce 16 partials (lanes >=16 padded neutral)
        const bool live = (tid < NP);
        float mi = live ? pm[b * NP + tid] : -INFINITY;
        float li = live ? pl[b * NP + tid] : 0.f;
        float M = mi;
#pragma unroll
        for (int off = 32; off >= 1; off >>= 1) M = fmaxf(M, __shfl_xor(M, off, 64));
        float e  = __expf(mi - M);       // exp(-inf)=0 for padding lanes
        float lw = li * e;
#pragma unroll
        for (int off = 32; off >= 1; off >>= 1) lw += __shfl_xor(lw, off, 64);
        if (live) s_e[tid] = e;
        if (tid == 0) { s_M = M; s_L = lw; }
    }
    __syncthreads();
    const float M  = s_M;
    const float rL = 1.0f / s_L;

    // context slice: d = slice*256 + tid
    const int d = slice * 256 + tid;
    const float* base = pctx + (size_t)b * NP * DD + d;
    float acc = 0.f;
#pragma unroll
    for (int i = 0; i < NP; i++) acc = fmaf(base[(size_t)i * DD], s_e[i], acc);
    out[(size_t)b * DD + d] = acc * rL;

    // weights: t = slice*512 + k*256 + tid
    float* wout = out + BB * DD;
#pragma unroll
    for (int k = 0; k < 2; k++) {
        int t = slice * 512 + k * 256 + tid;
        float w = __expf(scores[(size_t)b * TT + t] - M) * rL;
        wout[(size_t)b * TT + t] = w;
    }
}

extern "C" void kernel_launch(void* const* d_in, const int* in_sizes, int n_in,
                              void* d_out, int out_size, void* d_ws, size_t ws_size,
                              hipStream_t stream) {
    const float* query  = (const float*)d_in[0];
    const float* values = (const float*)d_in[1];
    float* ws = (float*)d_ws;
    float* out = (float*)d_out;

    attn_pass1<<<dim3(BB * BLOCKS_PER_B), dim3(256), 0, stream>>>(query, values, ws);
    attn_pass2<<<dim3(BB * 4), dim3(256), 0, stream>>>(ws, out);
}